// Round 12
// baseline (32.771 us; speedup 1.0000x reference)
//
#include <hip/hip_runtime.h>
#include <hip/hip_bf16.h>

// T=256, B=8, H1=512, U=64, H2=512, V=128
// out[b,t,u,v] = f[t,b,:]·W[:512,v] + g[b,u,:]·W[512:,v] + bias[v]; f_lens tail (8).
// K1 pgk (64 blocks): pg GEMM (proven proj3 path) -> Pg ws (256 KB).
// K2 fuse (512 blocks = b x 4t): per block — pg panel prefetch to LDS + OWN pf rows
//   via proven MFMA wave-split-K (scalar W gathers from raw f32 W), ONE barrier,
//   then proven 128 KB coalesced store phase. pf gather latency hides under the
//   co-resident block's store drain (2 blocks/CU, 40 KB LDS).
// Journal: R4/R5 no in-kernel cross-block sync. R7 no per-step barriers @1blk/CU.
//   R8/R9 ws-bf16-fragment-table -> MFMA: unexplained absmax — abandoned.
//   R10 VALU pf @2blk/CU load-latency bound. R11 store kernel already at floor;
//   the lever is removing proj3's 7us serialization, not store micro-opt.

typedef float  f32x4 __attribute__((ext_vector_type(4)));
typedef short  bh8   __attribute__((ext_vector_type(8)));

__device__ __forceinline__ unsigned short f2bf(float x) {
    unsigned u = __float_as_uint(x);
    return (unsigned short)((u + 0x7FFFu + ((u >> 16) & 1u)) >> 16);
}

__device__ __forceinline__ bh8 cvt8(f32x4 a, f32x4 b) {
    bh8 r;
    r[0] = (short)f2bf(a[0]); r[1] = (short)f2bf(a[1]);
    r[2] = (short)f2bf(a[2]); r[3] = (short)f2bf(a[3]);
    r[4] = (short)f2bf(b[0]); r[5] = (short)f2bf(b[1]);
    r[6] = (short)f2bf(b[2]); r[7] = (short)f2bf(b[3]);
    return r;
}

// ---------------- K1: pg GEMM, 64 blocks x 8 rows, wave-split-K (4x128) -------------
__global__ __launch_bounds__(256) void pgk(const float* __restrict__ G,
                                           const float* __restrict__ W,
                                           float* __restrict__ Pg) {
    __shared__ float sred[4][8][128];            // 16 KB
    const int tid = threadIdx.x;
    const int rows8 = blockIdx.x * 8;            // 0..504
    const int w = tid >> 6, lane = tid & 63, l15 = lane & 15, cc = lane >> 4;
    const float* arow = G + (rows8 + (l15 & 7)) * 512;

    f32x4 acc[8] = {};
#pragma unroll
    for (int kk = 0; kk < 4; ++kk) {
        const int k0 = w * 128 + kk * 32 + cc * 8;
        f32x4 a0 = *reinterpret_cast<const f32x4*>(arow + k0);
        f32x4 a1 = *reinterpret_cast<const f32x4*>(arow + k0 + 4);
        bh8 av = cvt8(a0, a1);
#pragma unroll
        for (int j = 0; j < 8; ++j) {
            const float* wsrc = W + (512 + k0) * 128 + (j * 16 + l15);
            bh8 bv;
#pragma unroll
            for (int i = 0; i < 8; ++i) bv[i] = (short)f2bf(wsrc[i * 128]);
            acc[j] = __builtin_amdgcn_mfma_f32_16x16x32_bf16(av, bv, acc[j], 0, 0, 0);
        }
    }
    if (cc < 2) {                                // D rows m = cc*4+q in [0,8); m>=8 dup
#pragma unroll
        for (int j = 0; j < 8; ++j)
#pragma unroll
            for (int q = 0; q < 4; ++q)
                sred[w][cc * 4 + q][j * 16 + l15] = acc[j][q];
    }
    __syncthreads();

    const int row = tid >> 5, colq = tid & 31;
    f32x4 s = *reinterpret_cast<const f32x4*>(&sred[0][row][colq * 4]);
    s += *reinterpret_cast<const f32x4*>(&sred[1][row][colq * 4]);
    s += *reinterpret_cast<const f32x4*>(&sred[2][row][colq * 4]);
    s += *reinterpret_cast<const f32x4*>(&sred[3][row][colq * 4]);
    *reinterpret_cast<f32x4*>(Pg + (rows8 + row) * 128 + colq * 4) = s;
}

// ---------------- K2: fused pf-MFMA + broadcast store, 512 blocks = (b, 4t) ---------
__global__ __launch_bounds__(256) void fuse(const float* __restrict__ F,
                                            const float* __restrict__ W,
                                            const float* __restrict__ Pg,
                                            const float* __restrict__ bias,
                                            const int* __restrict__ f_lens,
                                            float* __restrict__ out,
                                            int lens_off) {
    __shared__ float sred[4][4][128];    //  8 KB (pf partials)
    __shared__ float pgs[64 * 128];      // 32 KB (pg panel)

    const int tid = threadIdx.x;
    const int b  = blockIdx.x >> 6;
    const int t0 = (blockIdx.x & 63) * 4;
    const int w = tid >> 6, lane = tid & 63, l15 = lane & 15, cc = lane >> 4;

    // ---- issue pg panel prefetch (hides under pf gather/MFMA phase) ----
    const f32x4* pgsrc = reinterpret_cast<const f32x4*>(Pg + b * 8192);
    f32x4 pgin[8];
#pragma unroll
    for (int i = 0; i < 8; ++i) pgin[i] = pgsrc[i * 256 + tid];

    // ---- pf via MFMA (proj3 path): rows t0..t0+3, dup x4 in the 16-row tile ----
    const float* arow = F + ((t0 + (l15 & 3)) * 8 + b) * 512;   // f is [T][B][H1]
    f32x4 acc[8] = {};
#pragma unroll
    for (int kk = 0; kk < 4; ++kk) {
        const int k0 = w * 128 + kk * 32 + cc * 8;
        f32x4 a0 = *reinterpret_cast<const f32x4*>(arow + k0);
        f32x4 a1 = *reinterpret_cast<const f32x4*>(arow + k0 + 4);
        bh8 av = cvt8(a0, a1);
#pragma unroll
        for (int j = 0; j < 8; ++j) {
            const float* wsrc = W + k0 * 128 + (j * 16 + l15);
            bh8 bv;
#pragma unroll
            for (int i = 0; i < 8; ++i) bv[i] = (short)f2bf(wsrc[i * 128]);
            acc[j] = __builtin_amdgcn_mfma_f32_16x16x32_bf16(av, bv, acc[j], 0, 0, 0);
        }
    }
    if (cc == 0) {                       // D rows m = q in [0,4); m>=4 duplicate m&3
#pragma unroll
        for (int j = 0; j < 8; ++j)
#pragma unroll
            for (int q = 0; q < 4; ++q)
                sred[w][q][j * 16 + l15] = acc[j][q];
    }

    // ---- park pg panel in LDS ----
#pragma unroll
    for (int i = 0; i < 8; ++i)
        *reinterpret_cast<f32x4*>(&pgs[(i * 256 + tid) * 4]) = pgin[i];

    __syncthreads();

    // ---- reduce pf + store phase: 128 KB coalesced ----
    const int vq = tid & 31, ug = tid >> 5;
    const f32x4 bi = *reinterpret_cast<const f32x4*>(bias + vq * 4);
    f32x4 pfv[4];
#pragma unroll
    for (int t2 = 0; t2 < 4; ++t2) {
        f32x4 s = *reinterpret_cast<const f32x4*>(&sred[0][t2][vq * 4]);
        s += *reinterpret_cast<const f32x4*>(&sred[1][t2][vq * 4]);
        s += *reinterpret_cast<const f32x4*>(&sred[2][t2][vq * 4]);
        s += *reinterpret_cast<const f32x4*>(&sred[3][t2][vq * 4]);
        pfv[t2] = s + bi;
    }

    float* ob = out + (size_t)(b * 256 + t0) * 8192;
#pragma unroll
    for (int ui = 0; ui < 8; ++ui) {
        const int u = ui * 8 + ug;
        f32x4 pgv = *reinterpret_cast<const f32x4*>(&pgs[u * 128 + vq * 4]);
#pragma unroll
        for (int t2 = 0; t2 < 4; ++t2)
            *reinterpret_cast<f32x4*>(ob + (t2 * 64 + u) * 128 + vq * 4) = pfv[t2] + pgv;
    }

    if (blockIdx.x == 0 && tid < 8) out[lens_off + tid] = (float)f_lens[tid];
}

extern "C" void kernel_launch(void* const* d_in, const int* in_sizes, int n_in,
                              void* d_out, int out_size, void* d_ws, size_t ws_size,
                              hipStream_t stream) {
    const float* f      = (const float*)d_in[0];
    const int*   f_lens = (const int*)  d_in[1];
    const float* g      = (const float*)d_in[2];
    // d_in[3] = g_lens (unused by reference output)
    const float* W      = (const float*)d_in[4];
    const float* bias   = (const float*)d_in[5];
    float* out = (float*)d_out;

    float* Pg = (float*)d_ws;                                  // 512*128*4 = 256 KB

    pgk <<<dim3(64),  dim3(256), 0, stream>>>(g, W, Pg);
    fuse<<<dim3(512), dim3(256), 0, stream>>>(f, W, Pg, bias, f_lens, out, out_size - 8);
}

// Round 13
// 23.803 us; speedup vs baseline: 1.3768x; 1.3768x over previous
//
#include <hip/hip_runtime.h>
#include <hip/hip_bf16.h>

// T=256, B=8, H1=512, U=64, H2=512, V=128
// out[b,t,u,v] = f[t,b,:]·W[:512,v] + g[b,u,:]·W[512:,v] + bias[v]; f_lens tail (8).
// K1 proj4 (160 blocks x 16 rows): P GEMM, wave-split-K (4x128), B-fragments via
//   proven scalar gathers from raw f32 W; 16-row tiles halve per-CU TA load vs
//   proj3's 320x8 (1 block/CU, B amortized over 16 rows). R2-proven geometry +
//   R6-proven gather path.
// K2 bcast (2048 blocks = 1 t-row): R6-verbatim broadcast-store (panel L2-hot).
// Journal: R4/R5 no in-kernel cross-block sync (fences nuke write BW). R7 no
//   per-step barriers @1blk/CU. R8/R9 ws-bf16-fragment-table -> MFMA: absmax
//   anomalies — abandoned. R10/R12: pf-in-consumer never amortizes (VALU or
//   MFMA-gather) — two-kernel structure is final; optimize proj TA cost instead.

typedef float  f32x4 __attribute__((ext_vector_type(4)));
typedef short  bh8   __attribute__((ext_vector_type(8)));

__device__ __forceinline__ unsigned short f2bf(float x) {
    unsigned u = __float_as_uint(x);
    return (unsigned short)((u + 0x7FFFu + ((u >> 16) & 1u)) >> 16);
}

__device__ __forceinline__ bh8 cvt8(f32x4 a, f32x4 b) {
    bh8 r;
    r[0] = (short)f2bf(a[0]); r[1] = (short)f2bf(a[1]);
    r[2] = (short)f2bf(a[2]); r[3] = (short)f2bf(a[3]);
    r[4] = (short)f2bf(b[0]); r[5] = (short)f2bf(b[1]);
    r[6] = (short)f2bf(b[2]); r[7] = (short)f2bf(b[3]);
    return r;
}

// ---------------- K1: P GEMM, 160 blocks x 16 rows, wave-split-K (4x128) ------------
// P rows 0..2047: pf (r = b*256+t);  rows 2048..2559: pg (r = 2048+b*64+u).
__global__ __launch_bounds__(256) void proj4(const float* __restrict__ F,
                                             const float* __restrict__ G,
                                             const float* __restrict__ W,
                                             float* __restrict__ P) {
    __shared__ float sred[4][16][128];           // 32 KB

    const int tid = threadIdx.x;
    const int rows16 = blockIdx.x * 16;          // P row base
    const bool isF = rows16 < 2048;
    const int koff = isF ? 0 : 512;
    const int w = tid >> 6, lane = tid & 63, l15 = lane & 15, cc = lane >> 4;

    const int rr = rows16 + l15;                 // 16 real rows
    const float* arow = isF ? F + (((rr & 255) << 3) + (rr >> 8)) * 512   // f[t][b][:]
                            : G + (rr - 2048) * 512;                      // g[b*64+u][:]

    f32x4 acc[8] = {};
#pragma unroll
    for (int kk = 0; kk < 4; ++kk) {
        const int k0 = w * 128 + kk * 32 + cc * 8;
        f32x4 a0 = *reinterpret_cast<const f32x4*>(arow + k0);
        f32x4 a1 = *reinterpret_cast<const f32x4*>(arow + k0 + 4);
        bh8 av = cvt8(a0, a1);
#pragma unroll
        for (int j = 0; j < 8; ++j) {
            const float* wsrc = W + (koff + k0) * 128 + (j * 16 + l15);
            bh8 bv;
#pragma unroll
            for (int i = 0; i < 8; ++i) bv[i] = (short)f2bf(wsrc[i * 128]);
            acc[j] = __builtin_amdgcn_mfma_f32_16x16x32_bf16(av, bv, acc[j], 0, 0, 0);
        }
    }
    // D rows m = cc*4+q in [0,16), all real
#pragma unroll
    for (int j = 0; j < 8; ++j)
#pragma unroll
        for (int q = 0; q < 4; ++q)
            sred[w][cc * 4 + q][j * 16 + l15] = acc[j][q];
    __syncthreads();

    // reduce 4 waves, write 16 rows: thread -> (row = tid>>4, 8 cols at (tid&15)*8)
    const int row = tid >> 4, colq = tid & 15;
    f32x4 s0 = {}, s1 = {};
#pragma unroll
    for (int ww = 0; ww < 4; ++ww) {
        s0 += *reinterpret_cast<const f32x4*>(&sred[ww][row][colq * 8]);
        s1 += *reinterpret_cast<const f32x4*>(&sred[ww][row][colq * 8 + 4]);
    }
    float* pdst = P + (rows16 + row) * 128 + colq * 8;
    *reinterpret_cast<f32x4*>(pdst)     = s0;
    *reinterpret_cast<f32x4*>(pdst + 4) = s1;
}

// ---------------- K2: broadcast add + stream out + lens tail (R6 verbatim) ----------
__global__ __launch_bounds__(256) void bcast(const float* __restrict__ P,
                                             const float* __restrict__ bias,
                                             const int* __restrict__ f_lens,
                                             float* __restrict__ out,
                                             int lens_off) {
    const int r   = blockIdx.x;        // b*256 + t
    const int tid = threadIdx.x;
    const int b   = r >> 8;
    const int vq  = tid & 31;          // float4 index in V
    const int u0  = tid >> 5;          // 0..7

    f32x4 pf = *reinterpret_cast<const f32x4*>(P + r * 128 + vq * 4);
    f32x4 bi = *reinterpret_cast<const f32x4*>(bias + vq * 4);
    pf += bi;

    const float* pg = P + (2048 + b * 64) * 128;
    float* ob = out + (size_t)r * 8192;

#pragma unroll
    for (int i = 0; i < 8; ++i) {
        int u = u0 * 8 + i;
        f32x4 v = *reinterpret_cast<const f32x4*>(pg + u * 128 + vq * 4);
        v += pf;
        *reinterpret_cast<f32x4*>(ob + u * 128 + vq * 4) = v;
    }

    if (r == 0 && tid < 8) out[lens_off + tid] = (float)f_lens[tid];
}

extern "C" void kernel_launch(void* const* d_in, const int* in_sizes, int n_in,
                              void* d_out, int out_size, void* d_ws, size_t ws_size,
                              hipStream_t stream) {
    const float* f      = (const float*)d_in[0];
    const int*   f_lens = (const int*)  d_in[1];
    const float* g      = (const float*)d_in[2];
    // d_in[3] = g_lens (unused by reference output)
    const float* W      = (const float*)d_in[4];
    const float* bias   = (const float*)d_in[5];
    float* out = (float*)d_out;

    float* P = (float*)d_ws;                                   // 2560*128*4 = 1.25 MB

    proj4<<<dim3(160),  dim3(256), 0, stream>>>(f, g, W, P);
    bcast<<<dim3(2048), dim3(256), 0, stream>>>(P, bias, f_lens, out, out_size - 8);
}